// Round 3
// baseline (634.583 us; speedup 1.0000x reference)
//
#include <hip/hip_runtime.h>
#include <float.h>

#define NT 32768
#define DIM 2048
#define NE 64
#define NWAVES 8
#define KW (DIM / NWAVES)    // 256 k-steps per wave
#define TPB 64               // tokens per block (= lanes per wave)
#define LSTR 65              // padded reduction stride (conflict-free ds_add)

typedef __attribute__((ext_vector_type(16))) float f16v;

// wt[k*NE + e] = gw[e*DIM + k]   (512 KB into d_ws)
__global__ void transpose_w(const float* __restrict__ gw, float* __restrict__ wt) {
    int idx = blockIdx.x * 256 + threadIdx.x;   // idx = k*64 + e
    int k = idx >> 6, e = idx & 63;
    wt[idx] = gw[(size_t)e * DIM + k];
}

__global__ __launch_bounds__(512, 4)
void router_main(const float* __restrict__ x, const float* __restrict__ wt,
                 float* __restrict__ out) {
    __shared__ float red[TPB * LSTR];

    const int tid  = threadIdx.x;
    const int lane = tid & 63;           // lane == local token
    const int wid  = tid >> 6;           // wave == k-slice
    const int tblk = blockIdx.x * TPB;

    for (int i = tid; i < TPB * LSTR; i += 512) red[i] = 0.f;
    __syncthreads();

    float acc[NE];
#pragma unroll
    for (int e = 0; e < NE; ++e) acc[e] = 0.f;

    const int kw0 = wid * KW;
    const float* xp = x + (size_t)(tblk + lane) * DIM + kw0;
    const f16v* wq = (const f16v*)(wt + (size_t)kw0 * NE);   // 4 f16v per k

    float4 xv = *(const float4*)(xp);
    for (int kg = 0; kg < KW; kg += 4) {
        float4 xn = make_float4(0.f, 0.f, 0.f, 0.f);
        if (kg + 4 < KW) xn = *(const float4*)(xp + kg + 4);   // prefetch
#pragma unroll
        for (int kk = 0; kk < 4; ++kk) {
            const f16v w0 = wq[(kg + kk) * 4 + 0];   // uniform -> s_load_dwordx16
            const f16v w1 = wq[(kg + kk) * 4 + 1];
            const f16v w2 = wq[(kg + kk) * 4 + 2];
            const f16v w3 = wq[(kg + kk) * 4 + 3];
            const float xk = (kk == 0) ? xv.x : (kk == 1) ? xv.y
                           : (kk == 2) ? xv.z : xv.w;
#pragma unroll
            for (int e = 0; e < 16; ++e) {
                acc[e     ] = fmaf(w0[e], xk, acc[e     ]);
                acc[e + 16] = fmaf(w1[e], xk, acc[e + 16]);
                acc[e + 32] = fmaf(w2[e], xk, acc[e + 32]);
                acc[e + 48] = fmaf(w3[e], xk, acc[e + 48]);
            }
        }
        xv = xn;
    }

    // merge K-split partials: conflict-free ds_add_f32 (stride 65)
#pragma unroll
    for (int e = 0; e < NE; ++e)
        atomicAdd(&red[lane * LSTR + e], acc[e]);
    __syncthreads();

    // ---- epilogue: 8 threads per token, top-2 + softmax ----
    float* mout = out;
    float* wout = out + (size_t)NT * NE;
    float* iout = wout + (size_t)NT * 2;

    const int tl  = tid >> 3;       // local token 0..63
    const int sub = tid & 7;        // expert-segment 0..7
    const int tok = tblk + tl;

    float v[8];
#pragma unroll
    for (int j = 0; j < 8; ++j) v[j] = red[tl * LSTR + sub * 8 + j];

    float m1 = -FLT_MAX, m2 = -FLT_MAX; int i1 = NE, i2 = NE;
#pragma unroll
    for (int j = 0; j < 8; ++j) {
        float val = v[j]; int e = sub * 8 + j;
        if (val > m1)      { m2 = m1; i2 = i1; m1 = val; i1 = e; }
        else if (val > m2) { m2 = val; i2 = e; }
    }
#pragma unroll
    for (int off = 1; off <= 4; off <<= 1) {
        float om1 = __shfl_xor(m1, off, 64);
        int   oi1 = __shfl_xor(i1, off, 64);
        float om2 = __shfl_xor(m2, off, 64);
        int   oi2 = __shfl_xor(i2, off, 64);
        bool selfFirst = (m1 > om1) || (m1 == om1 && i1 < oi1);
        if (selfFirst) {
            bool keep = (m2 > om1) || (m2 == om1 && i2 < oi1);
            if (!keep) { m2 = om1; i2 = oi1; }
        } else {
            bool c = (m1 > om2) || (m1 == om2 && i1 < oi2);
            if (c) { m2 = m1; i2 = i1; } else { m2 = om2; i2 = oi2; }
            m1 = om1; i1 = oi1;
        }
    }

    float ed  = expf(m2 - m1);
    float inv = 1.f / (1.f + ed);

    float mv[8];
#pragma unroll
    for (int j = 0; j < 8; ++j) {
        int e = sub * 8 + j;
        mv[j] = (e == i1 || e == i2) ? 1.f : 0.f;
    }
    float* mrow = mout + (size_t)tok * NE + sub * 8;
    *(float4*)(mrow)     = make_float4(mv[0], mv[1], mv[2], mv[3]);
    *(float4*)(mrow + 4) = make_float4(mv[4], mv[5], mv[6], mv[7]);

    if (sub == 0) {
        *(float2*)(wout + 2 * tok) = make_float2(inv, ed * inv);
        *(float2*)(iout + 2 * tok) = make_float2((float)i1, (float)i2);
    }
}

extern "C" void kernel_launch(void* const* d_in, const int* in_sizes, int n_in,
                              void* d_out, int out_size, void* d_ws, size_t ws_size,
                              hipStream_t stream) {
    const float* x  = (const float*)d_in[0];
    const float* gw = (const float*)d_in[1];
    float* out = (float*)d_out;
    float* wt  = (float*)d_ws;                  // 512 KB transposed weights

    transpose_w<<<dim3((DIM * NE) / 256), dim3(256), 0, stream>>>(gw, wt);
    router_main<<<dim3(NT / TPB), dim3(512), 0, stream>>>(x, wt, out);
}

// Round 4
// 206.047 us; speedup vs baseline: 3.0798x; 3.0798x over previous
//
#include <hip/hip_runtime.h>
#include <float.h>

#define NT 32768
#define DIM 2048
#define NE 64
#define NWAVES 4
#define KW (DIM / NWAVES)   // 512 k per wave
#define TPB 64              // tokens per block
#define RSTR 68             // padded reduction stride (floats)

typedef __attribute__((ext_vector_type(16))) float f16v;

// wt[k][e] = gw[e][k], both phases coalesced via LDS tile
__global__ __launch_bounds__(256)
void transpose_w(const float* __restrict__ gw, float* __restrict__ wt) {
    __shared__ float ls[64][65];
    const int k0 = blockIdx.x * 64;
    const int r  = threadIdx.x >> 2;          // load: expert row; store: local k
    const int c0 = (threadIdx.x & 3) * 16;
#pragma unroll
    for (int j = 0; j < 16; j += 4) {
        float4 v = *(const float4*)(gw + (size_t)r * DIM + k0 + c0 + j);
        ls[r][c0 + j]     = v.x;
        ls[r][c0 + j + 1] = v.y;
        ls[r][c0 + j + 2] = v.z;
        ls[r][c0 + j + 3] = v.w;
    }
    __syncthreads();
    float* dst = wt + (size_t)(k0 + r) * NE + c0;
#pragma unroll
    for (int j = 0; j < 16; j += 4) {
        *(float4*)(dst + j) = make_float4(ls[c0 + j][r], ls[c0 + j + 1][r],
                                          ls[c0 + j + 2][r], ls[c0 + j + 3][r]);
    }
}

__global__ __launch_bounds__(256, 2)
void router_main(const float* __restrict__ x, const float* __restrict__ wt,
                 float* __restrict__ out) {
    __shared__ float red[NWAVES][TPB][RSTR];   // 69.6 KB -> 2 blocks/CU

    const int tid  = threadIdx.x;
    const int lane = tid & 63;                 // lane == local token
    const int wid  = tid >> 6;
    const int kq   = __builtin_amdgcn_readfirstlane(wid);  // uniform k-quarter
    const int tblk = blockIdx.x * TPB;

    float acc[NE];
#pragma unroll
    for (int e = 0; e < NE; ++e) acc[e] = 0.f;

    const float* xp = x + (size_t)(tblk + lane) * DIM + kq * KW;
    const float* wp = wt + (size_t)kq * KW * NE;           // uniform base

    float4 xa = *(const float4*)(xp);
    float4 xb = *(const float4*)(xp + 4);
    for (int kg = 0; kg < KW; kg += 8) {
        float4 xc = make_float4(0.f, 0.f, 0.f, 0.f);
        float4 xd = make_float4(0.f, 0.f, 0.f, 0.f);
        if (kg + 8 < KW) {
            xc = *(const float4*)(xp + kg + 8);
            xd = *(const float4*)(xp + kg + 12);
        }
#pragma unroll
        for (int kk = 0; kk < 8; ++kk) {
            const f16v* wk = (const f16v*)(wp + (size_t)(kg + kk) * NE); // uniform
            const f16v w0 = wk[0];
            const f16v w1 = wk[1];
            const f16v w2 = wk[2];
            const f16v w3 = wk[3];
            const float xk = (kk == 0) ? xa.x : (kk == 1) ? xa.y
                           : (kk == 2) ? xa.z : (kk == 3) ? xa.w
                           : (kk == 4) ? xb.x : (kk == 5) ? xb.y
                           : (kk == 6) ? xb.z : xb.w;
#pragma unroll
            for (int e = 0; e < 16; ++e) {
                acc[e     ] = fmaf(w0[e], xk, acc[e     ]);
                acc[e + 16] = fmaf(w1[e], xk, acc[e + 16]);
                acc[e + 32] = fmaf(w2[e], xk, acc[e + 32]);
                acc[e + 48] = fmaf(w3[e], xk, acc[e + 48]);
            }
        }
        xa = xc; xb = xd;
    }

    // deposit partials (k-quarter slices), deterministic merge in epilogue
#pragma unroll
    for (int e = 0; e < NE; e += 4)
        *(float4*)&red[wid][lane][e] =
            make_float4(acc[e], acc[e + 1], acc[e + 2], acc[e + 3]);
    __syncthreads();

    // ---- epilogue: 4 threads per token, 16 experts each ----
    float* mout = out;                              // (NT,64) mask
    float* wout = out + (size_t)NT * NE;            // (NT,2) weights
    float* iout = wout + (size_t)NT * 2;            // (NT,2) indices (as float)

    const int t   = tid >> 2;                       // local token 0..63
    const int sub = tid & 3;                        // 16-expert segment
    const int tok = tblk + t;

    float vsum[16];
#pragma unroll
    for (int j = 0; j < 16; j += 4) {
        float4 a = *(const float4*)&red[0][t][sub * 16 + j];
        float4 b = *(const float4*)&red[1][t][sub * 16 + j];
        float4 c = *(const float4*)&red[2][t][sub * 16 + j];
        float4 d = *(const float4*)&red[3][t][sub * 16 + j];
        vsum[j]     = ((a.x + b.x) + c.x) + d.x;
        vsum[j + 1] = ((a.y + b.y) + c.y) + d.y;
        vsum[j + 2] = ((a.z + b.z) + c.z) + d.z;
        vsum[j + 3] = ((a.w + b.w) + c.w) + d.w;
    }

    // local top-2 (ascending e, strict > keeps lowest index on ties)
    float m1 = -FLT_MAX, m2 = -FLT_MAX; int i1 = NE, i2 = NE;
#pragma unroll
    for (int j = 0; j < 16; ++j) {
        float val = vsum[j]; int e = sub * 16 + j;
        if (val > m1)      { m2 = m1; i2 = i1; m1 = val; i1 = e; }
        else if (val > m2) { m2 = val; i2 = e; }
    }
    // merge across the 4 threads of this token (lanes 4t..4t+3, same wave)
#pragma unroll
    for (int off = 1; off <= 2; off <<= 1) {
        float om1 = __shfl_xor(m1, off, 64);
        int   oi1 = __shfl_xor(i1, off, 64);
        float om2 = __shfl_xor(m2, off, 64);
        int   oi2 = __shfl_xor(i2, off, 64);
        bool selfFirst = (m1 > om1) || (m1 == om1 && i1 < oi1);
        if (selfFirst) {
            bool keep = (m2 > om1) || (m2 == om1 && i2 < oi1);
            if (!keep) { m2 = om1; i2 = oi1; }
        } else {
            bool c = (m1 > om2) || (m1 == om2 && i1 < oi2);
            if (c) { m2 = m1; i2 = i1; } else { m2 = om2; i2 = oi2; }
            m1 = om1; i1 = oi1;
        }
    }

    float ed  = expf(m2 - m1);
    float inv = 1.f / (1.f + ed);

    // mask: each thread writes its contiguous 16-expert segment
    float* mrow = mout + (size_t)tok * NE + sub * 16;
#pragma unroll
    for (int j = 0; j < 16; j += 4) {
        float4 mv;
        mv.x = ((sub * 16 + j)     == i1 || (sub * 16 + j)     == i2) ? 1.f : 0.f;
        mv.y = ((sub * 16 + j + 1) == i1 || (sub * 16 + j + 1) == i2) ? 1.f : 0.f;
        mv.z = ((sub * 16 + j + 2) == i1 || (sub * 16 + j + 2) == i2) ? 1.f : 0.f;
        mv.w = ((sub * 16 + j + 3) == i1 || (sub * 16 + j + 3) == i2) ? 1.f : 0.f;
        *(float4*)(mrow + j) = mv;
    }

    if (sub == 0) {
        *(float2*)(wout + 2 * tok) = make_float2(inv, ed * inv);
        *(float2*)(iout + 2 * tok) = make_float2((float)i1, (float)i2);
    }
}

extern "C" void kernel_launch(void* const* d_in, const int* in_sizes, int n_in,
                              void* d_out, int out_size, void* d_ws, size_t ws_size,
                              hipStream_t stream) {
    const float* x  = (const float*)d_in[0];
    const float* gw = (const float*)d_in[1];
    float* out = (float*)d_out;
    float* wt  = (float*)d_ws;                 // 512 KB transposed weights

    transpose_w<<<dim3(DIM / 64), dim3(256), 0, stream>>>(gw, wt);
    router_main<<<dim3(NT / TPB), dim3(256), 0, stream>>>(x, wt, out);
}

// Round 5
// 157.697 us; speedup vs baseline: 4.0241x; 1.3066x over previous
//
#include <hip/hip_runtime.h>
#include <float.h>

#define NT 32768
#define DIM 2048
#define NE 64
#define KSPLIT 4
#define KW (DIM / KSPLIT)    // 512 k per wave
#define TPB 64               // tokens per block

typedef __attribute__((ext_vector_type(16))) float f16v;

// wt[k][e] = gw[e][k], both phases coalesced via LDS tile
__global__ __launch_bounds__(256)
void transpose_w(const float* __restrict__ gw, float* __restrict__ wt) {
    __shared__ float ls[64][65];
    const int k0 = blockIdx.x * 64;
    const int r  = threadIdx.x >> 2;
    const int c0 = (threadIdx.x & 3) * 16;
#pragma unroll
    for (int j = 0; j < 16; j += 4) {
        float4 v = *(const float4*)(gw + (size_t)r * DIM + k0 + c0 + j);
        ls[r][c0 + j]     = v.x;
        ls[r][c0 + j + 1] = v.y;
        ls[r][c0 + j + 2] = v.z;
        ls[r][c0 + j + 3] = v.w;
    }
    __syncthreads();
    float* dst = wt + (size_t)(k0 + r) * NE + c0;
#pragma unroll
    for (int j = 0; j < 16; j += 4) {
        *(float4*)(dst + j) = make_float4(ls[c0 + j][r], ls[c0 + j + 1][r],
                                          ls[c0 + j + 2][r], ls[c0 + j + 3][r]);
    }
}

__global__ __launch_bounds__(512, 4)
void router_main(const float* __restrict__ x, const float* __restrict__ wt,
                 float* __restrict__ out) {
    // 64 KB: [k-quarter][token][expert], columns XOR-swizzled per row
    __shared__ float red[KSPLIT][TPB][NE];

    const int tid  = threadIdx.x;
    const int lane = tid & 63;                              // lane == local token
    const int wid  = __builtin_amdgcn_readfirstlane(tid >> 6);
    const int kq   = wid >> 1;                              // k-quarter 0..3
    const int eh   = wid & 1;                               // expert half 0..1
    const int tblk = blockIdx.x * TPB;

    float acc[32];
#pragma unroll
    for (int e = 0; e < 32; ++e) acc[e] = 0.f;

    const float* xp = x + (size_t)(tblk + lane) * DIM + kq * KW;
    const float* wp = wt + (size_t)kq * KW * NE + eh * 32;  // uniform

    // w double-buffer in SGPRs: 2 x 32 floats
    f16v w0 = *(const f16v*)(wp);
    f16v w1 = *(const f16v*)(wp + 16);

    float4 xa = *(const float4*)(xp);
    float4 xb = *(const float4*)(xp + 4);

    for (int kg = 0; kg < KW; kg += 8) {
        float4 xc = make_float4(0.f, 0.f, 0.f, 0.f);
        float4 xd = make_float4(0.f, 0.f, 0.f, 0.f);
        if (kg + 8 < KW) {
            xc = *(const float4*)(xp + kg + 8);
            xd = *(const float4*)(xp + kg + 12);
        }
#pragma unroll
        for (int kk = 0; kk < 8; ++kk) {
            const int kn = (kg + kk + 1) & (KW - 1);        // next k (wraps once)
            const f16v n0 = *(const f16v*)(wp + (size_t)kn * NE);
            const f16v n1 = *(const f16v*)(wp + (size_t)kn * NE + 16);
            const float xk = (kk == 0) ? xa.x : (kk == 1) ? xa.y
                           : (kk == 2) ? xa.z : (kk == 3) ? xa.w
                           : (kk == 4) ? xb.x : (kk == 5) ? xb.y
                           : (kk == 6) ? xb.z : xb.w;
#pragma unroll
            for (int e = 0; e < 16; ++e) {
                acc[e]      = fmaf(w0[e], xk, acc[e]);
                acc[e + 16] = fmaf(w1[e], xk, acc[e + 16]);
            }
            w0 = n0; w1 = n1;
        }
        xa = xc; xb = xd;
    }

    // deposit: wave (kq,eh) owns red[kq][lane][eh*32..eh*32+31], swizzled cols
#pragma unroll
    for (int c = 0; c < 8; ++c) {
        const int col = (eh * 32 + c * 4) ^ ((lane & 7) << 2);
        *(float4*)&red[kq][lane][col] =
            make_float4(acc[4 * c], acc[4 * c + 1], acc[4 * c + 2], acc[4 * c + 3]);
    }
    __syncthreads();

    // ---- epilogue: 8 threads per token, 8 experts each ----
    float* mout = out;                              // (NT,64) mask
    float* wout = out + (size_t)NT * NE;            // (NT,2) weights
    float* iout = wout + (size_t)NT * 2;            // (NT,2) indices (as float)

    const int t   = tid >> 3;                       // local token 0..63
    const int sub = tid & 7;                        // 8-expert segment
    const int tok = tblk + t;

    float vsum[8];
#pragma unroll
    for (int h = 0; h < 2; ++h) {
        const int c   = sub * 2 + h;                // global float4 chunk 0..15
        const int col = (4 * c) ^ ((t & 7) << 2);
        float4 a = *(const float4*)&red[0][t][col];
        float4 b = *(const float4*)&red[1][t][col];
        float4 d = *(const float4*)&red[2][t][col];
        float4 e = *(const float4*)&red[3][t][col];
        vsum[4 * h]     = ((a.x + b.x) + d.x) + e.x;
        vsum[4 * h + 1] = ((a.y + b.y) + d.y) + e.y;
        vsum[4 * h + 2] = ((a.z + b.z) + d.z) + e.z;
        vsum[4 * h + 3] = ((a.w + b.w) + d.w) + e.w;
    }

    // local top-2 (ascending e, strict > keeps lowest index on ties)
    float m1 = -FLT_MAX, m2 = -FLT_MAX; int i1 = NE, i2 = NE;
#pragma unroll
    for (int j = 0; j < 8; ++j) {
        float val = vsum[j]; int e = sub * 8 + j;
        if (val > m1)      { m2 = m1; i2 = i1; m1 = val; i1 = e; }
        else if (val > m2) { m2 = val; i2 = e; }
    }
    // merge across the 8 threads of this token (consecutive lanes, same wave)
#pragma unroll
    for (int off = 1; off <= 4; off <<= 1) {
        float om1 = __shfl_xor(m1, off, 64);
        int   oi1 = __shfl_xor(i1, off, 64);
        float om2 = __shfl_xor(m2, off, 64);
        int   oi2 = __shfl_xor(i2, off, 64);
        bool selfFirst = (m1 > om1) || (m1 == om1 && i1 < oi1);
        if (selfFirst) {
            bool keep = (m2 > om1) || (m2 == om1 && i2 < oi1);
            if (!keep) { m2 = om1; i2 = oi1; }
        } else {
            bool c = (m1 > om2) || (m1 == om2 && i1 < oi2);
            if (c) { m2 = m1; i2 = i1; } else { m2 = om2; i2 = oi2; }
            m1 = om1; i1 = oi1;
        }
    }

    float ed  = expf(m2 - m1);
    float inv = 1.f / (1.f + ed);

    // mask: each thread writes its contiguous 8-expert segment
    float* mrow = mout + (size_t)tok * NE + sub * 8;
    float4 mv0, mv1;
    mv0.x = (sub * 8     == i1 || sub * 8     == i2) ? 1.f : 0.f;
    mv0.y = (sub * 8 + 1 == i1 || sub * 8 + 1 == i2) ? 1.f : 0.f;
    mv0.z = (sub * 8 + 2 == i1 || sub * 8 + 2 == i2) ? 1.f : 0.f;
    mv0.w = (sub * 8 + 3 == i1 || sub * 8 + 3 == i2) ? 1.f : 0.f;
    mv1.x = (sub * 8 + 4 == i1 || sub * 8 + 4 == i2) ? 1.f : 0.f;
    mv1.y = (sub * 8 + 5 == i1 || sub * 8 + 5 == i2) ? 1.f : 0.f;
    mv1.z = (sub * 8 + 6 == i1 || sub * 8 + 6 == i2) ? 1.f : 0.f;
    mv1.w = (sub * 8 + 7 == i1 || sub * 8 + 7 == i2) ? 1.f : 0.f;
    *(float4*)(mrow)     = mv0;
    *(float4*)(mrow + 4) = mv1;

    if (sub == 0) {
        *(float2*)(wout + 2 * tok) = make_float2(inv, ed * inv);
        *(float2*)(iout + 2 * tok) = make_float2((float)i1, (float)i2);
    }
}

extern "C" void kernel_launch(void* const* d_in, const int* in_sizes, int n_in,
                              void* d_out, int out_size, void* d_ws, size_t ws_size,
                              hipStream_t stream) {
    const float* x  = (const float*)d_in[0];
    const float* gw = (const float*)d_in[1];
    float* out = (float*)d_out;
    float* wt  = (float*)d_ws;                 // 512 KB transposed weights

    transpose_w<<<dim3(DIM / 64), dim3(256), 0, stream>>>(gw, wt);
    router_main<<<dim3(NT / TPB), dim3(512), 0, stream>>>(x, wt, out);
}